// Round 4
// baseline (560.505 us; speedup 1.0000x reference)
//
#include <hip/hip_runtime.h>
#include <hip/hip_bf16.h>
#include <cstdint>

// ---------------------------------------------------------------------------
// Gemma4 MoE FFN. N=4096 tokens, H=1024, ID=4096, IM=512, E=8, top-2.
// Round 3: gathered/grouped expert GEMMs (4x FLOP cut) + BK=64 XOR-swizzled
// conflict-free GEMM core + split-K dense down.
// ---------------------------------------------------------------------------

typedef __attribute__((ext_vector_type(8))) short short8;
typedef __attribute__((ext_vector_type(4))) float floatx4;
typedef const void __attribute__((address_space(1)))* gptr_t;
typedef void __attribute__((address_space(3)))* sptr_t;

#define BF16 __hip_bfloat16

__device__ __forceinline__ float gelu_tanh(float x) {
  float x3 = x * x * x;
  float t = tanhf(0.7978845608028654f * (x + 0.044715f * x3));
  return 0.5f * x * (1.f + t);
}

// ---------------------------------------------------------------------------
// BK=64 tile [128 rows][64 bf16] = 16KB, 8 granules of 16B per row.
// Swizzle: LDS(row, g) holds global granule (row, g ^ (row&7)).
// Stage: linear LDS dest (global_load_lds), pre-swizzled per-lane source.
// Read: same XOR -> lanes 0..15 (rows r..r+15, fixed gk) hit banks
// 4*(gk^(r&7)) -> all 8 granule slots -> only 2-way aliasing (free).
// ---------------------------------------------------------------------------
__device__ __forceinline__ void stage64(const BF16* __restrict__ g, BF16* lds,
                                        int ldg, int wave, int lane) {
  const int rsub = lane >> 3;  // 0..7
  const int gcol = lane & 7;   // 0..7
#pragma unroll
  for (int j = 0; j < 4; ++j) {
    int row = wave * 32 + j * 8 + rsub;
    const BF16* src = g + (size_t)row * ldg + ((gcol ^ rsub) * 8);
    BF16* dst = lds + (wave * 32 + j * 8) * 64;  // wave-uniform; HW adds lane*16B
    __builtin_amdgcn_global_load_lds((gptr_t)src, (sptr_t)dst, 16, 0, 0);
  }
}

__device__ __forceinline__ short8 frag64(const BF16* lds, int fr, int kh, int lane) {
  int gk = kh * 4 + (lane >> 4);
  return *(const short8*)&lds[fr * 64 + ((gk ^ (fr & 7)) * 8)];
}

// ---------------------------------------------------------------------------
// Dual up-GEMM (gelu(A@Bg)*(A@Bu)), K=1024, out bf16.
// GROUPED=0: A[4096][1024], by=row tile, out [4096][4096]
// GROUPED=1: A=A_g[9216][1024], desc[by]={expert,row0}, B rows e*512+c,
//            out [9216][512], epilogue * row_w[r]
// ---------------------------------------------------------------------------
template <int GROUPED>
__launch_bounds__(256, 2)
__global__ void gemm_up_k(const BF16* __restrict__ A, const BF16* __restrict__ Bg,
                          const BF16* __restrict__ Bu, const int2* __restrict__ desc,
                          const float* __restrict__ row_w, BF16* __restrict__ out) {
  constexpr int K = 1024;
  __shared__ __align__(16) BF16 lds_a[128 * 64];
  __shared__ __align__(16) BF16 lds_g[128 * 64];
  __shared__ __align__(16) BF16 lds_u[128 * 64];
  int e = 0, r0;
  const int c0 = blockIdx.x * 128;
  if (GROUPED) {
    int2 d = desc[blockIdx.y];
    if (d.x < 0) return;
    e = d.x;
    r0 = d.y;
  } else {
    r0 = blockIdx.y * 128;
  }
  const int lane = threadIdx.x & 63, wave = threadIdx.x >> 6;
  const int wr = wave >> 1, wc = wave & 1;
  const BF16* Ar = A + (size_t)r0 * K;
  const size_t brow = (size_t)(GROUPED ? e * 512 + c0 : c0) * K;
  const BF16* Bgr = Bg + brow;
  const BF16* Bur = Bu + brow;

  floatx4 accg[4][4] = {};
  floatx4 accu[4][4] = {};

  for (int kt = 0; kt < K / 64; ++kt) {
    stage64(Ar + kt * 64, lds_a, K, wave, lane);
    stage64(Bgr + kt * 64, lds_g, K, wave, lane);
    stage64(Bur + kt * 64, lds_u, K, wave, lane);
    __syncthreads();
#pragma unroll
    for (int kh = 0; kh < 2; ++kh) {
      short8 af[4], gf[4], uf[4];
#pragma unroll
      for (int mi = 0; mi < 4; ++mi)
        af[mi] = frag64(lds_a, wr * 64 + mi * 16 + (lane & 15), kh, lane);
#pragma unroll
      for (int ni = 0; ni < 4; ++ni) {
        gf[ni] = frag64(lds_g, wc * 64 + ni * 16 + (lane & 15), kh, lane);
        uf[ni] = frag64(lds_u, wc * 64 + ni * 16 + (lane & 15), kh, lane);
      }
#pragma unroll
      for (int mi = 0; mi < 4; ++mi)
#pragma unroll
        for (int ni = 0; ni < 4; ++ni) {
          accg[mi][ni] = __builtin_amdgcn_mfma_f32_16x16x32_bf16(af[mi], gf[ni], accg[mi][ni], 0, 0, 0);
          accu[mi][ni] = __builtin_amdgcn_mfma_f32_16x16x32_bf16(af[mi], uf[ni], accu[mi][ni], 0, 0, 0);
        }
    }
    __syncthreads();
  }

  constexpr int NOUT = GROUPED ? 512 : 4096;
#pragma unroll
  for (int mi = 0; mi < 4; ++mi)
#pragma unroll
    for (int ni = 0; ni < 4; ++ni)
#pragma unroll
      for (int j = 0; j < 4; ++j) {
        int r = r0 + wr * 64 + mi * 16 + (lane >> 4) * 4 + j;
        int c = c0 + wc * 64 + ni * 16 + (lane & 15);
        float h = gelu_tanh(accg[mi][ni][j]) * accu[mi][ni][j];
        if (GROUPED) h *= row_w[r];
        out[(size_t)r * NOUT + c] = __float2bfloat16(h);
      }
}

// ---------------------------------------------------------------------------
// Down GEMM.
// GROUPED=0: A=HBUF[4096][4096], B=WddT[1024][4096], split-K via z (2 parts,
//            2048 each), f32 atomicAdd into outF [4096][1024] (pre-zeroed)
// GROUPED=1: A=HBUF_e[9216][512], desc, B=WdeT_e+e*1024*512 [1024][512],
//            K=512, bf16 store outB [9216][1024]
// ---------------------------------------------------------------------------
template <int GROUPED>
__launch_bounds__(256, 2)
__global__ void gemm_down_k(const BF16* __restrict__ A, const BF16* __restrict__ B,
                            const int2* __restrict__ desc, float* __restrict__ outF,
                            BF16* __restrict__ outB) {
  __shared__ __align__(16) BF16 lds_a[128 * 64];
  __shared__ __align__(16) BF16 lds_b[128 * 64];
  int e = 0, r0;
  const int c0 = blockIdx.x * 128;
  if (GROUPED) {
    int2 d = desc[blockIdx.y];
    if (d.x < 0) return;
    e = d.x;
    r0 = d.y;
  } else {
    r0 = blockIdx.y * 128;
  }
  const int ldA = GROUPED ? 512 : 4096;
  const int kiters = GROUPED ? 8 : 32;
  const int k0 = GROUPED ? 0 : blockIdx.z * 2048;
  const int lane = threadIdx.x & 63, wave = threadIdx.x >> 6;
  const int wr = wave >> 1, wc = wave & 1;
  const BF16* Ar = A + (size_t)r0 * ldA + k0;
  const BF16* Br = (GROUPED ? B + (size_t)e * 1024 * 512 + (size_t)c0 * 512
                            : B + (size_t)c0 * 4096 + k0);

  floatx4 acc[4][4] = {};

  for (int kt = 0; kt < kiters; ++kt) {
    stage64(Ar + kt * 64, lds_a, ldA, wave, lane);
    stage64(Br + kt * 64, lds_b, ldA, wave, lane);
    __syncthreads();
#pragma unroll
    for (int kh = 0; kh < 2; ++kh) {
      short8 af[4], bf[4];
#pragma unroll
      for (int mi = 0; mi < 4; ++mi)
        af[mi] = frag64(lds_a, wr * 64 + mi * 16 + (lane & 15), kh, lane);
#pragma unroll
      for (int ni = 0; ni < 4; ++ni)
        bf[ni] = frag64(lds_b, wc * 64 + ni * 16 + (lane & 15), kh, lane);
#pragma unroll
      for (int mi = 0; mi < 4; ++mi)
#pragma unroll
        for (int ni = 0; ni < 4; ++ni)
          acc[mi][ni] = __builtin_amdgcn_mfma_f32_16x16x32_bf16(af[mi], bf[ni], acc[mi][ni], 0, 0, 0);
    }
    __syncthreads();
  }

#pragma unroll
  for (int mi = 0; mi < 4; ++mi)
#pragma unroll
    for (int ni = 0; ni < 4; ++ni)
#pragma unroll
      for (int j = 0; j < 4; ++j) {
        int r = r0 + wr * 64 + mi * 16 + (lane >> 4) * 4 + j;
        int c = c0 + wc * 64 + ni * 16 + (lane & 15);
        if (GROUPED)
          outB[(size_t)r * 1024 + c] = __float2bfloat16(acc[mi][ni][j]);
        else
          atomicAdd(&outF[(size_t)r * 1024 + c], acc[mi][ni][j]);
      }
}

// ---------------------------------------------------------------------------
// Router: rmsnorm stats, xr (w_pre2, bf16), logits, softmax, top-2.
// One wave per token. Writes top_i/top_w pairs + expert histogram.
// ---------------------------------------------------------------------------
__global__ void router_kernel(const float* __restrict__ residual,
                              const float* __restrict__ w_pre2,
                              const float* __restrict__ router_scale,
                              const float* __restrict__ per_expert_scale,
                              const float* __restrict__ Wr,  // [1024][8]
                              BF16* __restrict__ xr,         // [4096][1024]
                              int* __restrict__ top_i, float* __restrict__ top_w,
                              int* __restrict__ counts) {
  const int lane = threadIdx.x & 63, wave = threadIdx.x >> 6;
  const int n = blockIdx.x * 4 + wave;
  const float* res = residual + (size_t)n * 1024;

  float v[16];
  float ss = 0.f;
#pragma unroll
  for (int i = 0; i < 16; ++i) {
    v[i] = res[lane + i * 64];
    ss += v[i] * v[i];
  }
#pragma unroll
  for (int off = 32; off; off >>= 1) ss += __shfl_xor(ss, off);
  const float inv = rsqrtf(ss * (1.f / 1024.f) + 1e-6f);

  float logits[8] = {};
#pragma unroll
  for (int i = 0; i < 16; ++i) {
    int h = lane + i * 64;
    float nv = v[i] * inv;
    xr[(size_t)n * 1024 + h] = __float2bfloat16(nv * w_pre2[h]);
    float yv = nv * router_scale[h];
#pragma unroll
    for (int ex = 0; ex < 8; ++ex) logits[ex] += yv * Wr[h * 8 + ex];
  }
#pragma unroll
  for (int ex = 0; ex < 8; ++ex)
#pragma unroll
    for (int off = 32; off; off >>= 1) logits[ex] += __shfl_xor(logits[ex], off);

  if (lane == 0) {
    const float hscale = 0.03125f;  // 1024^-0.5
    float mx = -1e30f;
#pragma unroll
    for (int ex = 0; ex < 8; ++ex) {
      logits[ex] *= hscale;
      mx = fmaxf(mx, logits[ex]);
    }
    float p[8];
#pragma unroll
    for (int ex = 0; ex < 8; ++ex) p[ex] = __expf(logits[ex] - mx);
    int i0 = 0;
#pragma unroll
    for (int ex = 1; ex < 8; ++ex)
      if (p[ex] > p[i0]) i0 = ex;
    int i1 = -1;
#pragma unroll
    for (int ex = 0; ex < 8; ++ex)
      if (ex != i0 && (i1 < 0 || p[ex] > p[i1])) i1 = ex;
    float w0 = p[i0], w1 = p[i1];
    float swv = w0 + w1;
    w0 = w0 / swv * per_expert_scale[i0];
    w1 = w1 / swv * per_expert_scale[i1];
    top_i[n * 2] = i0;
    top_i[n * 2 + 1] = i1;
    top_w[n * 2] = w0;
    top_w[n * 2 + 1] = w1;
    atomicAdd(&counts[i0], 1);
    atomicAdd(&counts[i1], 1);
  }
}

__global__ void init_counts(int* counts) {
  if (threadIdx.x < 8) counts[threadIdx.x] = 0;
}

// Single block: 128-aligned prefix offsets, tile descriptors (72, tail=-1),
// cursor=0, row_token=-1 / row_w=0 for all 9216 padded rows.
__global__ void moe_scan(const int* __restrict__ counts, int* __restrict__ offsets,
                         int* __restrict__ cursor, int2* __restrict__ desc,
                         int* __restrict__ row_token, float* __restrict__ row_w) {
  if (threadIdx.x == 0) {
    int acc = 0, t = 0;
    for (int e = 0; e < 8; ++e) {
      offsets[e] = acc;
      cursor[e] = 0;
      int cnt = counts[e];
      int ntile = (cnt + 127) >> 7;
      for (int k = 0; k < ntile; ++k) desc[t++] = make_int2(e, acc + k * 128);
      acc += ntile * 128;
    }
    for (; t < 72; ++t) desc[t] = make_int2(-1, 0);
  }
  for (int i = threadIdx.x; i < 9216; i += blockDim.x) {
    row_token[i] = -1;
    row_w[i] = 0.f;
  }
}

// One thread per (token, k) pair: claim a slot in the expert's segment.
__global__ void moe_assign(const int* __restrict__ top_i, const float* __restrict__ top_w,
                           const int* __restrict__ offsets, int* __restrict__ cursor,
                           int* __restrict__ row_token, float* __restrict__ row_w,
                           int* __restrict__ pair_pos) {
  const int p = blockIdx.x * blockDim.x + threadIdx.x;  // 0..8191
  const int e = top_i[p];
  const int pos = offsets[e] + atomicAdd(&cursor[e], 1);
  row_token[pos] = p >> 1;
  row_w[pos] = top_w[p];
  pair_pos[p] = pos;
}

// Gather: A_g[pos] = xr[token] (zeros for padding rows).
__global__ void moe_gather(const BF16* __restrict__ xr, const int* __restrict__ row_token,
                           BF16* __restrict__ A_g) {
  const int r = blockIdx.x;
  const int t = row_token[r];
  uint2* dst = (uint2*)(A_g + (size_t)r * 1024) + threadIdx.x;
  if (t < 0) {
    uint2 z;
    z.x = 0u;
    z.y = 0u;
    *dst = z;
  } else {
    *dst = *((const uint2*)(xr + (size_t)t * 1024) + threadIdx.x);
  }
}

__global__ void zero_f32(float* __restrict__ p) {
  const size_t i = ((size_t)blockIdx.x * blockDim.x + threadIdx.x) * 4;
  float4 z = {0.f, 0.f, 0.f, 0.f};
  *(float4*)(p + i) = z;
}

// ---------------------------------------------------------------------------
// Finalize: routed[n] = down_e[p0] + down_e[p1];
// out = rmsnorm(dense)*w_post1 + rmsnorm(routed)*w_post2
// ---------------------------------------------------------------------------
__global__ void finalize_kernel(const float* __restrict__ dp, const BF16* __restrict__ de,
                                const int* __restrict__ pair_pos,
                                const float* __restrict__ w1, const float* __restrict__ w2,
                                float* __restrict__ out) {
  const int n = blockIdx.x, t = threadIdx.x;
  const int p0 = pair_pos[n * 2], p1 = pair_pos[n * 2 + 1];
  float d[4], r[4];
  float ssd = 0.f, ssr = 0.f;
#pragma unroll
  for (int i = 0; i < 4; ++i) {
    int h = t + i * 256;
    d[i] = dp[(size_t)n * 1024 + h];
    r[i] = __bfloat162float(de[(size_t)p0 * 1024 + h]) +
           __bfloat162float(de[(size_t)p1 * 1024 + h]);
    ssd += d[i] * d[i];
    ssr += r[i] * r[i];
  }
#pragma unroll
  for (int off = 32; off; off >>= 1) {
    ssd += __shfl_xor(ssd, off);
    ssr += __shfl_xor(ssr, off);
  }
  __shared__ float sd[4], sr[4];
  int wave = t >> 6, lane = t & 63;
  if (lane == 0) {
    sd[wave] = ssd;
    sr[wave] = ssr;
  }
  __syncthreads();
  ssd = sd[0] + sd[1] + sd[2] + sd[3];
  ssr = sr[0] + sr[1] + sr[2] + sr[3];
  const float invd = rsqrtf(ssd * (1.f / 1024.f) + 1e-6f);
  const float invr = rsqrtf(ssr * (1.f / 1024.f) + 1e-6f);
#pragma unroll
  for (int i = 0; i < 4; ++i) {
    int h = t + i * 256;
    out[(size_t)n * 1024 + h] = d[i] * invd * w1[h] + r[i] * invr * w2[h];
  }
}

// ---------------------------------------------------------------------------
// f32 -> bf16 transpose (batched): out[b][c][r] = bf16(in[b][r][c])
// ---------------------------------------------------------------------------
__global__ void transpose_cvt(const float* __restrict__ in, BF16* __restrict__ out,
                              int rows, int cols) {
  __shared__ float tile[32][33];
  const size_t boff = (size_t)blockIdx.z * rows * cols;
  in += boff;
  out += boff;
  const int c0 = blockIdx.x * 32, r0 = blockIdx.y * 32;
#pragma unroll
  for (int i = 0; i < 4; ++i)
    tile[threadIdx.y + i * 8][threadIdx.x] =
        in[(size_t)(r0 + threadIdx.y + i * 8) * cols + c0 + threadIdx.x];
  __syncthreads();
#pragma unroll
  for (int i = 0; i < 4; ++i)
    out[(size_t)(c0 + threadIdx.y + i * 8) * rows + r0 + threadIdx.x] =
        __float2bfloat16(tile[threadIdx.x][threadIdx.y + i * 8]);
}

__global__ void cvt_bf16_kernel(const float* __restrict__ in, BF16* __restrict__ out) {
  const size_t i = ((size_t)blockIdx.x * blockDim.x + threadIdx.x) * 4;
  float4 v = *(const float4*)(in + i);
  BF16 o[4] = {__float2bfloat16(v.x), __float2bfloat16(v.y),
               __float2bfloat16(v.z), __float2bfloat16(v.w)};
  *(uint2*)(out + i) = *(const uint2*)o;
}

// ---------------------------------------------------------------------------
extern "C" void kernel_launch(void* const* d_in, const int* in_sizes, int n_in,
                              void* d_out, int out_size, void* d_ws, size_t ws_size,
                              hipStream_t stream) {
  const float* x = (const float*)d_in[0];
  const float* res = (const float*)d_in[1];
  const float* Wg_d = (const float*)d_in[2];
  const float* Wu_d = (const float*)d_in[3];
  const float* Wd_d = (const float*)d_in[4];
  const float* w_post1 = (const float*)d_in[5];
  const float* w_pre2 = (const float*)d_in[6];
  const float* w_post2 = (const float*)d_in[7];
  const float* router_scale = (const float*)d_in[8];
  const float* per_expert_scale = (const float*)d_in[9];
  const float* Wr = (const float*)d_in[10];
  const float* Wg_e = (const float*)d_in[11];
  const float* Wu_e = (const float*)d_in[12];
  const float* Wd_e = (const float*)d_in[13];
  float* out = (float*)d_out;

  char* ws = (char*)d_ws;
  const size_t MB = 1ull << 20;
  BF16* x_b = (BF16*)(ws + 0 * MB);           // [4096][1024]
  BF16* xr_b = (BF16*)(ws + 8 * MB);          // [4096][1024]
  float* dense_pre = (float*)(ws + 16 * MB);  // [4096][1024] f32 (aliases WgdT/WudT)
  BF16* WgdT = (BF16*)(ws + 16 * MB);         // [4096][1024] (dead after dense up)
  BF16* WudT = (BF16*)(ws + 24 * MB);         // [4096][1024]
  BF16* WddT = (BF16*)(ws + 32 * MB);         // [1024][4096]
  BF16* WgeT = (BF16*)(ws + 40 * MB);         // [8][512][1024]
  BF16* WueT = (BF16*)(ws + 48 * MB);         // [8][512][1024]
  BF16* WdeT_e = (BF16*)(ws + 56 * MB);       // [8][1024][512]
  BF16* HBUF = (BF16*)(ws + 64 * MB);         // [4096][4096] dense hidden
  BF16* down_e = (BF16*)(ws + 64 * MB);       // [9216][1024] (reuse after dense down)
  BF16* A_g = (BF16*)(ws + 96 * MB);          // [9216][1024] gathered tokens
  BF16* HBUF_e = (BF16*)(ws + 114 * MB);      // [9216][512]
  char* S = ws + 123 * MB;
  int* top_i = (int*)(S);                 // [8192]
  float* top_w = (float*)(S + 32 * 1024); // [8192]
  int* pair_pos = (int*)(S + 64 * 1024);  // [8192]
  int* row_token = (int*)(S + 96 * 1024); // [9216]
  float* row_w = (float*)(S + 136 * 1024);// [9216]
  int* counts = (int*)(S + 176 * 1024);   // [8]
  int* offsets = counts + 8;
  int* cursor = counts + 16;
  int2* desc = (int2*)(counts + 24);      // [72]

  dim3 tb(32, 8);
  // pre-pass: conversions + weight transposes (B^T layout, bf16)
  cvt_bf16_kernel<<<4096, 256, 0, stream>>>(x, x_b);
  transpose_cvt<<<dim3(128, 32, 1), tb, 0, stream>>>(Wg_d, WgdT, 1024, 4096);
  transpose_cvt<<<dim3(128, 32, 1), tb, 0, stream>>>(Wu_d, WudT, 1024, 4096);
  transpose_cvt<<<dim3(32, 128, 1), tb, 0, stream>>>(Wd_d, WddT, 4096, 1024);
  transpose_cvt<<<dim3(16, 32, 8), tb, 0, stream>>>(Wg_e, WgeT, 1024, 512);
  transpose_cvt<<<dim3(16, 32, 8), tb, 0, stream>>>(Wu_e, WueT, 1024, 512);
  transpose_cvt<<<dim3(32, 16, 8), tb, 0, stream>>>(Wd_e, WdeT_e, 512, 1024);

  // router + MoE bookkeeping
  init_counts<<<1, 64, 0, stream>>>(counts);
  router_kernel<<<1024, 256, 0, stream>>>(res, w_pre2, router_scale, per_expert_scale,
                                          Wr, xr_b, top_i, top_w, counts);
  moe_scan<<<1, 256, 0, stream>>>(counts, offsets, cursor, desc, row_token, row_w);
  moe_assign<<<32, 256, 0, stream>>>(top_i, top_w, offsets, cursor, row_token, row_w,
                                     pair_pos);
  moe_gather<<<9216, 256, 0, stream>>>(xr_b, row_token, A_g);

  // dense path
  gemm_up_k<0><<<dim3(32, 32), 256, 0, stream>>>(x_b, WgdT, WudT, nullptr, nullptr, HBUF);
  zero_f32<<<4096, 256, 0, stream>>>(dense_pre);
  gemm_down_k<0><<<dim3(8, 32, 2), 256, 0, stream>>>(HBUF, WddT, nullptr, dense_pre,
                                                     nullptr);

  // expert path (grouped; combine weight folded into hidden)
  gemm_up_k<1><<<dim3(4, 72), 256, 0, stream>>>(A_g, WgeT, WueT, desc, row_w, HBUF_e);
  gemm_down_k<1><<<dim3(8, 72), 256, 0, stream>>>(HBUF_e, WdeT_e, desc, nullptr, down_e);

  // out = rmsnorm(dense)*w_post1 + rmsnorm(routed)*w_post2
  finalize_kernel<<<4096, 256, 0, stream>>>(dense_pre, down_e, pair_pos, w_post1,
                                            w_post2, out);
}